// Round 14
// baseline (3554.750 us; speedup 1.0000x reference)
//
#include <hip/hip_runtime.h>

#define NPTS 65536

typedef __bf16 bf16_t;
typedef __bf16 bf16x8 __attribute__((ext_vector_type(8)));
typedef float f32x16 __attribute__((ext_vector_type(16)));

#define MFMA32(A, B, C) __builtin_amdgcn_mfma_f32_32x32x16_bf16(A, B, C, 0, 0, 0)

__device__ __forceinline__ float relu(float v) { return v > 0.f ? v : 0.f; }

// ======================================================================
// 128-pt-block layouts (R8-verified):
// Activation (C ch): octet idx = ((b*(C/16)+kc)*4+mi)*64 + l
//   point = b*128 + mi*32 + (l&31); channel = kc*16 + (l>>5)*8 + j
// Weight (N x K): octet idx = (st*(K/16)+kc)*64 + l; n = st*32+(l&31); k = kc*16+(l>>5)*8+j
// 64-pt internal contract (R10-verified): octet idx = (kc*2+mi)*64+l
// ======================================================================

struct PrepSeg { const float* src; bf16_t* h; bf16_t* l; int SW; int K; int nblk; };
struct PrepAll { PrepSeg seg[6]; };

__global__ __launch_bounds__(256) void kprep(PrepAll pa) {
  int blk = blockIdx.x, i = 0;
  while (blk >= pa.seg[i].nblk) { blk -= pa.seg[i].nblk; ++i; }
  const PrepSeg sg = pa.seg[i];
  int t8 = blk * 256 + threadIdx.x;
  int l = t8 & 63;
  int rest = t8 >> 6;
  int NKC = sg.K >> 4;
  int kc = rest % NKC, st = rest / NKC;
  int n = st * 32 + (l & 31);
  int k0 = kc * 16 + (l >> 5) * 8;
  const float* src = sg.src + (size_t)n * sg.SW + k0;
  bf16x8 hv, lv;
#pragma unroll
  for (int j = 0; j < 8; ++j) {
    float v = src[j];
    bf16_t h = (bf16_t)v;
    hv[j] = h; lv[j] = (bf16_t)(v - (float)h);
  }
  *(bf16x8*)(sg.h + (size_t)t8 * 8) = hv;
  *(bf16x8*)(sg.l + (size_t)t8 * 8) = lv;
}

// ============ k1a (verified): h1 = relu(x@W1.T+b1) in 128-pt activation order
__global__ __launch_bounds__(256, 2) void k1a(
    const float* __restrict__ x, const float* __restrict__ W1, const float* __restrict__ b1,
    bf16_t* __restrict__ h1h, bf16_t* __restrict__ h1l) {
  int p = blockIdx.x * 256 + threadIdx.x;
  float x0 = x[p * 3 + 0], x1 = x[p * 3 + 1], x2 = x[p * 3 + 2];
  int b = p >> 7, mi = (p >> 5) & 3, p31 = p & 31;
#pragma unroll
  for (int kc = 0; kc < 4; ++kc)
#pragma unroll
    for (int hbw = 0; hbw < 2; ++hbw) {
      bf16x8 hv, lv;
#pragma unroll
      for (int j = 0; j < 8; ++j) {
        int c = kc * 16 + hbw * 8 + j;
        float v = relu(fmaf(W1[c * 3], x0, fmaf(W1[c * 3 + 1], x1, fmaf(W1[c * 3 + 2], x2, b1[c]))));
        bf16_t h = (bf16_t)v;
        hv[j] = h; lv[j] = (bf16_t)(v - (float)h);
      }
      size_t off = (((size_t)(b * 4 + kc) * 4 + mi) * 64 + hbw * 32 + p31) * 8;
      *(bf16x8*)(h1h + off) = hv;
      *(bf16x8*)(h1l + off) = lv;
    }
}

// ============ gemmS (verified): D = W·X^T, 3-term split 32x32x16 bf16 MFMA
template <int PB, int K, int MODE>
__global__ __launch_bounds__(256, 3) void gemmS(
    const bf16_t* __restrict__ Ah, const bf16_t* __restrict__ Al,
    const bf16_t* __restrict__ Wh, const bf16_t* __restrict__ Wl,
    const float* __restrict__ bias, int nko,
    bf16_t* __restrict__ Oh, bf16_t* __restrict__ Ol,
    float* __restrict__ aux, const float* __restrict__ w8, const float* __restrict__ b8) {
  constexpr int WC = 4 / PB;
  constexpr int NKC = K / 16;
  constexpr int KG = 2;
  constexpr int NG = NKC / KG;
  __shared__ bf16_t smem[2][PB][2][KG * 2048];

  int tid = threadIdx.x;
  int lane = tid & 63;
  int w = __builtin_amdgcn_readfirstlane(tid >> 6);
  int rg = w / WC, cw = w % WC;
  int hb = lane >> 5, p31 = lane & 31;
  int bx = blockIdx.x;
  int st0 = blockIdx.y * WC + cw;
  int bblk = bx * PB + rg;

  f32x16 acc[4];
#pragma unroll
  for (int r = 0; r < 16; ++r) {
    float bv = bias[st0 * 32 + 8 * (r >> 2) + 4 * hb + (r & 3)];
#pragma unroll
    for (int mi = 0; mi < 4; ++mi) acc[mi][r] = bv;
  }

  auto stage = [&](int buf, int g) {
#pragma unroll
    for (int i = 0; i < PB * 4; ++i) {
      int u = i * 256 + tid;
      int rgs = u >> 10, rem = u & 1023;
      int t = rem >> 9, inner = rem & 511;
      const bf16_t* src = (t ? Al : Ah) +
          ((size_t)(bx * PB + rgs) * NKC + g * KG) * 2048 + inner * 8;
      *(bf16x8*)&smem[buf][rgs][t][inner * 8] = *(const bf16x8*)src;
    }
  };

  bf16x8 wch[KG], wcl[KG], wnh[KG], wnl[KG];
  auto wload = [&](int g, bf16x8* h, bf16x8* l) {
#pragma unroll
    for (int kcl = 0; kcl < KG; ++kcl) {
      size_t wo = (((size_t)st0 * NKC + g * KG + kcl) * 64 + lane) * 8;
      h[kcl] = *(const bf16x8*)(Wh + wo);
      l[kcl] = *(const bf16x8*)(Wl + wo);
    }
  };

  auto compute = [&](int buf, bf16x8* h, bf16x8* l) {
#pragma unroll
    for (int kcl = 0; kcl < KG; ++kcl)
#pragma unroll
      for (int mi = 0; mi < 4; ++mi) {
        const bf16_t* xp = &smem[buf][rg][0][((kcl * 4 + mi) * 64 + lane) * 8];
        bf16x8 xh = *(const bf16x8*)xp;
        bf16x8 xl = *(const bf16x8*)(xp + KG * 2048);
        acc[mi] = MFMA32(h[kcl], xh, acc[mi]);
        acc[mi] = MFMA32(l[kcl], xh, acc[mi]);
        acc[mi] = MFMA32(h[kcl], xl, acc[mi]);
      }
  };

  stage(0, 0);
  wload(0, wch, wcl);
  for (int g = 0; g < NG; ++g) {
    __syncthreads();
    if (g + 1 < NG) {
      stage((g + 1) & 1, g + 1);
      wload(g + 1, wnh, wnl);
    }
    compute(g & 1, wch, wcl);
#pragma unroll
    for (int kcl = 0; kcl < KG; ++kcl) { wch[kcl] = wnh[kcl]; wcl[kcl] = wnl[kcl]; }
  }

  if constexpr (MODE == 0) {
#pragma unroll
    for (int mi = 0; mi < 4; ++mi) {
      float a[16], rcv[8];
#pragma unroll
      for (int r = 0; r < 16; ++r) a[r] = relu(acc[mi][r]);
#pragma unroll
      for (int j = 0; j < 8; ++j) rcv[j] = __shfl_xor(hb ? a[j] : a[8 + j], 32);
      float o0[8], o1[8];
#pragma unroll
      for (int j = 0; j < 4; ++j) {
        o0[j]     = hb ? rcv[j]     : a[j];
        o0[4 + j] = hb ? a[8 + j]   : rcv[j];
        o1[j]     = hb ? rcv[4 + j] : a[4 + j];
        o1[4 + j] = hb ? a[12 + j]  : rcv[4 + j];
      }
      bf16x8 h0, l0, h1, l1;
#pragma unroll
      for (int j = 0; j < 8; ++j) {
        bf16_t x0 = (bf16_t)o0[j]; h0[j] = x0; l0[j] = (bf16_t)(o0[j] - (float)x0);
        bf16_t x1 = (bf16_t)o1[j]; h1[j] = x1; l1[j] = (bf16_t)(o1[j] - (float)x1);
      }
      int kco = st0 * 2 + hb;
      size_t ob = ((size_t)(bblk * nko + kco) * 4 + mi) * 64;
      *(bf16x8*)(Oh + (ob + p31) * 8)      = h0;
      *(bf16x8*)(Ol + (ob + p31) * 8)      = l0;
      *(bf16x8*)(Oh + (ob + 32 + p31) * 8) = h1;
      *(bf16x8*)(Ol + (ob + 32 + p31) * 8) = l1;
    }
  } else if constexpr (MODE == 1) {
#pragma unroll
    for (int r = 0; r < 16; ++r) {
      float m = relu(acc[0][r]);
#pragma unroll
      for (int mi = 1; mi < 4; ++mi) m = fmaxf(m, relu(acc[mi][r]));
#pragma unroll
      for (int off = 1; off < 32; off <<= 1) m = fmaxf(m, __shfl_xor(m, off));
      if (p31 == 0)
        aux[(size_t)bx * 1024 + st0 * 32 + 8 * (r >> 2) + 4 * hb + (r & 3)] = m;
    }
  } else {
    __shared__ float sp[4][128];
    float w8v[16];
#pragma unroll
    for (int r = 0; r < 16; ++r) w8v[r] = w8[st0 * 32 + 8 * (r >> 2) + 4 * hb + (r & 3)];
#pragma unroll
    for (int mi = 0; mi < 4; ++mi) {
      float s = 0.f;
#pragma unroll
      for (int r = 0; r < 16; ++r) s = fmaf(relu(acc[mi][r]), w8v[r], s);
      s += __shfl_xor(s, 32);
      if (hb == 0) sp[w][mi * 32 + p31] = s;
    }
    __syncthreads();
    if (tid < 128)
      aux[(size_t)bx * 128 + tid] = sp[0][tid] + sp[1][tid] + sp[2][tid] + sp[3][tid] + b8[0];
  }
}

// ============ kgmax: g[c] = max over 1024 rows of gpart[1024][1024]
__global__ __launch_bounds__(256) void kgmax(const float* __restrict__ gpart, float* __restrict__ g) {
  int t = blockIdx.x * 256 + threadIdx.x;  // 8192 threads: 1024 ch x 8 rowgroups
  int c = t & 1023, rg = t >> 10;
  const float* gp = gpart + (size_t)rg * 128 * 1024 + c;
  float m = 0.f;
#pragma unroll 8
  for (int r = 0; r < 128; ++r) m = fmaxf(m, gp[(size_t)r * 1024]);
  atomicMax((unsigned int*)(g + c), __float_as_uint(m));  // all values >= 0
}

// ============ kc5 (verified): c5[c] = W5[c][64:1088] @ g + b5[c]
__global__ __launch_bounds__(256) void kc5(
    const float* __restrict__ W5, const float* __restrict__ b5,
    const float* __restrict__ g, float* __restrict__ c5) {
  int tid = threadIdx.x;
  int ci = tid >> 3, kg = tid & 7;
  int c = blockIdx.x * 32 + ci;
  const float* wrow = W5 + (size_t)c * 1088 + 64 + kg * 128;
  const float* gp = g + kg * 128;
  float acc = 0.f;
#pragma unroll 8
  for (int k = 0; k < 128; ++k) acc += wrow[k] * gp[k];
#pragma unroll
  for (int off = 1; off <= 4; off <<= 1) acc += __shfl_xor(acc, off);
  if (kg == 0) c5[c] = acc + b5[c];
}

// ======================================================================
// Verified 64-pt helpers (R10/R11); wgemmC = chunked double-buffered weight loads.
// Outer chunk loops kept ROLLED (code-size hedge); inner bodies fully unrolled.
// ======================================================================

struct Oct { bf16x8 h0, l0, h1, l1; };
__device__ __forceinline__ Oct epi_pack(const f32x16& accv, int hb) {
  float a[16], rcv[8];
#pragma unroll
  for (int r = 0; r < 16; ++r) a[r] = relu(accv[r]);
#pragma unroll
  for (int j = 0; j < 8; ++j) rcv[j] = __shfl_xor(hb ? a[j] : a[8 + j], 32);
  float o0[8], o1[8];
#pragma unroll
  for (int j = 0; j < 4; ++j) {
    o0[j]     = hb ? rcv[j]     : a[j];
    o0[4 + j] = hb ? a[8 + j]   : rcv[j];
    o1[j]     = hb ? rcv[4 + j] : a[4 + j];
    o1[4 + j] = hb ? a[12 + j]  : rcv[4 + j];
  }
  Oct o;
#pragma unroll
  for (int j = 0; j < 8; ++j) {
    bf16_t x0 = (bf16_t)o0[j]; o.h0[j] = x0; o.l0[j] = (bf16_t)(o0[j] - (float)x0);
    bf16_t x1 = (bf16_t)o1[j]; o.h1[j] = x1; o.l1[j] = (bf16_t)(o1[j] - (float)x1);
  }
  return o;
}

__device__ __forceinline__ void epi_store_lds(const Oct& o, bf16_t* H, bf16_t* L, int ob, int p31) {
  *(bf16x8*)(H + (ob + p31) * 8)      = o.h0;
  *(bf16x8*)(H + (ob + 32 + p31) * 8) = o.h1;
  *(bf16x8*)(L + (ob + p31) * 8)      = o.l0;
  *(bf16x8*)(L + (ob + 32 + p31) * 8) = o.l1;
}

__device__ __forceinline__ void binit2(f32x16 acc[2], const float* bias, int base, int hb) {
#pragma unroll
  for (int r = 0; r < 16; ++r) {
    float bv = bias[base + 8 * (r >> 2) + 4 * hb + (r & 3)];
    acc[0][r] = bv; acc[1][r] = bv;
  }
}

template <int NKC>  // NKC multiple of 4
__device__ __forceinline__ void wgemmC(const bf16_t* __restrict__ Wh, const bf16_t* __restrict__ Wl,
                                       int st, const bf16_t* act, int loOff, int lane,
                                       f32x16 acc[2]) {
  constexpr int NCH = NKC / 4;
  bf16x8 bh[2][4], bl[2][4];
  auto ld = [&](int buf, int ch) {
#pragma unroll
    for (int k = 0; k < 4; ++k) {
      size_t wo = ((size_t)(st * NKC + ch * 4 + k) * 64 + lane) * 8;
      bh[buf][k] = *(const bf16x8*)(Wh + wo);
      bl[buf][k] = *(const bf16x8*)(Wl + wo);
    }
  };
  ld(0, 0);
#pragma unroll 1
  for (int ch = 0; ch < NCH; ++ch) {
    if (ch + 1 < NCH) ld((ch + 1) & 1, ch + 1);
#pragma unroll
    for (int k = 0; k < 4; ++k) {
      int kc = ch * 4 + k;
      bf16x8 xh[2], xl[2];
#pragma unroll
      for (int mi = 0; mi < 2; ++mi) {
        const bf16_t* xp = act + ((kc * 2 + mi) * 64 + lane) * 8;
        xh[mi] = *(const bf16x8*)xp; xl[mi] = *(const bf16x8*)(xp + loOff);
      }
#pragma unroll
      for (int mi = 0; mi < 2; ++mi) acc[mi] = MFMA32(bh[ch & 1][k], xh[mi], acc[mi]);
#pragma unroll
      for (int mi = 0; mi < 2; ++mi) acc[mi] = MFMA32(bl[ch & 1][k], xh[mi], acc[mi]);
#pragma unroll
      for (int mi = 0; mi < 2; ++mi) acc[mi] = MFMA32(bh[ch & 1][k], xl[mi], acc[mi]);
    }
  }
}

// ============ m34 v2: h2 -> y3 (LDS) -> L4+max -> gpart, 64-pt blocks,
// L4 weights double-buffered at half-strip (4 kc) granularity; maxima via LDS.
// Outer 16-iter loop kept rolled (code-size hedge).
__global__ __launch_bounds__(256, 3) void m34(
    const bf16_t* __restrict__ h2gh, const bf16_t* __restrict__ h2gl,
    const bf16_t* __restrict__ W3h, const bf16_t* __restrict__ W3l, const float* __restrict__ b3,
    const bf16_t* __restrict__ W4h, const bf16_t* __restrict__ W4l, const float* __restrict__ b4,
    float* __restrict__ gpart) {
  __shared__ __align__(16) bf16_t h2s[8192];   // hi [0,4096), lo [4096,8192) elems
  __shared__ __align__(16) bf16_t y3s[16384];  // hi [0,8192), lo [8192,16384)
  __shared__ float smax[1024];
  int tid = threadIdx.x, lane = tid & 63;
  int w = __builtin_amdgcn_readfirstlane(tid >> 6);
  int hb = lane >> 5, p31 = lane & 31;
  int b = blockIdx.x;
  int B = b >> 1, half = b & 1;  // 128-pt producer block B, 64-pt half

  // stage h2 (verbatim R10 remap)
#pragma unroll
  for (int i = 0; i < 4; ++i) {
    int u = i * 256 + tid;
    int t = u >> 9, rem = u & 511;
    int kcmi = rem >> 6, l = rem & 63;
    int kc = kcmi >> 1, mi2 = kcmi & 1;
    size_t so = ((size_t)((B * 4 + kc) * 4 + half * 2 + mi2) * 64 + l) * 8;
    const bf16_t* src = (t ? h2gl : h2gh) + so;
    *(bf16x8*)(h2s + t * 4096 + rem * 8) = *(const bf16x8*)src;
  }
  __syncthreads();

  // ---- L3: wave strip w, K=64
  {
    f32x16 a3[2];
    binit2(a3, b3, w * 32, hb);
    wgemmC<4>(W3h, W3l, w, h2s, 4096, lane, a3);
#pragma unroll
    for (int mi = 0; mi < 2; ++mi) {
      Oct o = epi_pack(a3[mi], hb);
      epi_store_lds(o, y3s, y3s + 8192, ((w * 2 + hb) * 2 + mi) * 64, p31);
    }
  }
  __syncthreads();

  // ---- L4 + max: flat (strip, half-K) iterations, weights prefetched 1 iter ahead
  {
    bf16x8 wah[2][4], wal[2][4];
    auto wld = [&](int buf, int it) {
      int st4 = (it >> 1) * 4 + w;
      int kcb = (it & 1) * 4;
#pragma unroll
      for (int kcl = 0; kcl < 4; ++kcl) {
        size_t wo = ((size_t)(st4 * 8 + kcb + kcl) * 64 + lane) * 8;
        wah[buf][kcl] = *(const bf16x8*)(W4h + wo);
        wal[buf][kcl] = *(const bf16x8*)(W4l + wo);
      }
    };
    wld(0, 0);
    f32x16 a4[2];
#pragma unroll 1
    for (int it = 0; it < 16; ++it) {
      if ((it & 1) == 0) binit2(a4, b4, ((it >> 1) * 4 + w) * 32, hb);
      if (it + 1 < 16) wld((it + 1) & 1, it + 1);
#pragma unroll
      for (int kcl = 0; kcl < 4; ++kcl) {
        int kc = (it & 1) * 4 + kcl;
        bf16x8 xh[2], xl[2];
#pragma unroll
        for (int mi = 0; mi < 2; ++mi) {
          const bf16_t* xp = y3s + ((kc * 2 + mi) * 64 + lane) * 8;
          xh[mi] = *(const bf16x8*)xp; xl[mi] = *(const bf16x8*)(xp + 8192);
        }
#pragma unroll
        for (int mi = 0; mi < 2; ++mi) a4[mi] = MFMA32(wah[it & 1][kcl], xh[mi], a4[mi]);
#pragma unroll
        for (int mi = 0; mi < 2; ++mi) a4[mi] = MFMA32(wal[it & 1][kcl], xh[mi], a4[mi]);
#pragma unroll
        for (int mi = 0; mi < 2; ++mi) a4[mi] = MFMA32(wah[it & 1][kcl], xl[mi], a4[mi]);
      }
      if (it & 1) {
        int st4 = (it >> 1) * 4 + w;
#pragma unroll
        for (int r = 0; r < 16; ++r) {
          float m = fmaxf(relu(a4[0][r]), relu(a4[1][r]));
#pragma unroll
          for (int off = 1; off < 32; off <<= 1) m = fmaxf(m, __shfl_xor(m, off));
          if (p31 == 0) smax[st4 * 32 + 8 * (r >> 2) + 4 * hb + (r & 3)] = m;
        }
      }
    }
  }
  __syncthreads();
#pragma unroll
  for (int i = 0; i < 4; ++i)
    gpart[(size_t)b * 1024 + i * 256 + tid] = smax[i * 256 + tid];
}

// ============ mega2: h2 -> z5 -> z6 -> z7 -> out (R10 structure; chunked weight prefetch)
__global__ __launch_bounds__(256, 2) void mega2(
    const bf16_t* __restrict__ h2gh, const bf16_t* __restrict__ h2gl,
    const bf16_t* __restrict__ W5h, const bf16_t* __restrict__ W5l, const float* __restrict__ c5,
    const bf16_t* __restrict__ W6h, const bf16_t* __restrict__ W6l, const float* __restrict__ b6,
    const bf16_t* __restrict__ W7h, const bf16_t* __restrict__ W7l, const float* __restrict__ b7,
    const float* __restrict__ w8, const float* __restrict__ b8v, float* __restrict__ out) {
  __shared__ __align__(16) bf16_t smem[32768];
  __shared__ float sp[4][64];
  int tid = threadIdx.x, lane = tid & 63;
  int w = __builtin_amdgcn_readfirstlane(tid >> 6);
  int hb = lane >> 5, p31 = lane & 31;
  int b = blockIdx.x;
  int B = b >> 1, half = b & 1;
  bf16_t* z5buf = smem + 8192;

#pragma unroll
  for (int i = 0; i < 4; ++i) {
    int u = i * 256 + tid;
    int t = u >> 9, rem = u & 511;
    int kcmi = rem >> 6, l = rem & 63;
    int kc = kcmi >> 1, mi2 = kcmi & 1;
    size_t so = ((size_t)((B * 4 + kc) * 4 + half * 2 + mi2) * 64 + l) * 8;
    const bf16_t* src = (t ? h2gl : h2gh) + so;
    *(bf16x8*)(smem + t * 4096 + rem * 8) = *(const bf16x8*)src;
  }
  __syncthreads();

  f32x16 z6a[2][2];
#pragma unroll
  for (int s = 0; s < 2; ++s)
#pragma unroll
    for (int r = 0; r < 16; ++r) {
      float bv = b6[(w * 2 + s) * 32 + 8 * (r >> 2) + 4 * hb + (r & 3)];
      z6a[s][0][r] = bv; z6a[s][1][r] = bv;
    }

#pragma unroll 1
  for (int g5 = 0; g5 < 4; ++g5) {
    int st5 = g5 * 4 + w;
    f32x16 a5[2];
    binit2(a5, c5, st5 * 32, hb);
    wgemmC<4>(W5h, W5l, st5, smem, 4096, lane, a5);
    __syncthreads();
#pragma unroll
    for (int mi = 0; mi < 2; ++mi) {
      Oct o = epi_pack(a5[mi], hb);
      epi_store_lds(o, z5buf, z5buf + 8192, ((w * 2 + hb) * 2 + mi) * 64, p31);
    }
    __syncthreads();
    // ---- L6 partial accumulate, kc chunked by 2, weights double-buffered
    bf16x8 w6h[2][2][2], w6l[2][2][2];  // [buf][s][kcl]
    auto ld6 = [&](int buf, int ch) {
#pragma unroll
      for (int s = 0; s < 2; ++s)
#pragma unroll
        for (int kcl = 0; kcl < 2; ++kcl) {
          size_t wo = ((size_t)((w * 2 + s) * 32 + g5 * 8 + ch * 2 + kcl) * 64 + lane) * 8;
          w6h[buf][s][kcl] = *(const bf16x8*)(W6h + wo);
          w6l[buf][s][kcl] = *(const bf16x8*)(W6l + wo);
        }
    };
    ld6(0, 0);
#pragma unroll 1
    for (int ch = 0; ch < 4; ++ch) {
      if (ch + 1 < 4) ld6((ch + 1) & 1, ch + 1);
#pragma unroll
      for (int kcl = 0; kcl < 2; ++kcl) {
        int kc = ch * 2 + kcl;
        bf16x8 xh[2], xl[2];
#pragma unroll
        for (int mi = 0; mi < 2; ++mi) {
          const bf16_t* xp = z5buf + ((kc * 2 + mi) * 64 + lane) * 8;
          xh[mi] = *(const bf16x8*)xp; xl[mi] = *(const bf16x8*)(xp + 8192);
        }
#pragma unroll
        for (int s = 0; s < 2; ++s)
#pragma unroll
          for (int mi = 0; mi < 2; ++mi)
            z6a[s][mi] = MFMA32(w6h[ch & 1][s][kcl], xh[mi], z6a[s][mi]);
#pragma unroll
        for (int s = 0; s < 2; ++s)
#pragma unroll
          for (int mi = 0; mi < 2; ++mi)
            z6a[s][mi] = MFMA32(w6l[ch & 1][s][kcl], xh[mi], z6a[s][mi]);
#pragma unroll
        for (int s = 0; s < 2; ++s)
#pragma unroll
          for (int mi = 0; mi < 2; ++mi)
            z6a[s][mi] = MFMA32(w6h[ch & 1][s][kcl], xl[mi], z6a[s][mi]);
      }
    }
  }
  __syncthreads();
#pragma unroll
  for (int s = 0; s < 2; ++s) {
    int kcb = (w * 2 + s) * 2 + hb;
#pragma unroll
    for (int mi = 0; mi < 2; ++mi) {
      Oct o = epi_pack(z6a[s][mi], hb);
      epi_store_lds(o, smem, smem + 16384, (kcb * 2 + mi) * 64, p31);
    }
  }
  __syncthreads();
  f32x16 a7[2];
  binit2(a7, b7, w * 32, hb);
  wgemmC<16>(W7h, W7l, w, smem, 16384, lane, a7);
  float w8v[16];
#pragma unroll
  for (int r = 0; r < 16; ++r) w8v[r] = w8[w * 32 + 8 * (r >> 2) + 4 * hb + (r & 3)];
#pragma unroll
  for (int mi = 0; mi < 2; ++mi) {
    float s = 0.f;
#pragma unroll
    for (int r = 0; r < 16; ++r) s = fmaf(relu(a7[mi][r]), w8v[r], s);
    s += __shfl_xor(s, 32);
    if (hb == 0) sp[w][mi * 32 + p31] = s;
  }
  __syncthreads();
  if (tid < 64)
    out[b * 64 + tid] = sp[0][tid] + sp[1][tid] + sp[2][tid] + sp[3][tid] + b8v[0];
}

extern "C" void kernel_launch(void* const* d_in, const int* in_sizes, int n_in,
                              void* d_out, int out_size, void* d_ws, size_t ws_size,
                              hipStream_t stream) {
  const float* x  = (const float*)d_in[0];
  const float* W1 = (const float*)d_in[1];  const float* b1 = (const float*)d_in[2];
  const float* W2 = (const float*)d_in[3];  const float* b2 = (const float*)d_in[4];
  const float* W3 = (const float*)d_in[5];  const float* b3 = (const float*)d_in[6];
  const float* W4 = (const float*)d_in[7];  const float* b4 = (const float*)d_in[8];
  const float* W5 = (const float*)d_in[9];  const float* b5 = (const float*)d_in[10];
  const float* W6 = (const float*)d_in[11]; const float* b6 = (const float*)d_in[12];
  const float* W7 = (const float*)d_in[13]; const float* b7 = (const float*)d_in[14];
  const float* W8 = (const float*)d_in[15]; const float* b8 = (const float*)d_in[16];
  float* out = (float*)d_out;

  const size_t MB = 1ull << 20;
  char* ws = (char*)d_ws;
  bf16_t* h2h = (bf16_t*)(ws + 128 * MB);  bf16_t* h2l = (bf16_t*)(ws + 136 * MB);
  bf16_t* h1h = (bf16_t*)(ws + 144 * MB);  bf16_t* h1l = (bf16_t*)(ws + 152 * MB);
  float* gpart = (float*)(ws + 180 * MB);
  float* g     = (float*)(ws + 210 * MB);
  float* c5    = (float*)(ws + 210 * MB + 4096);
  char* wb = ws + 210 * MB + 65536;
  bf16_t* W2h = (bf16_t*)(wb);             bf16_t* W2l = (bf16_t*)(wb + 8192);
  bf16_t* W3h = (bf16_t*)(wb + 16384);     bf16_t* W3l = (bf16_t*)(wb + 32768);
  bf16_t* W4h = (bf16_t*)(wb + 49152);     bf16_t* W4l = (bf16_t*)(wb + 311296);
  bf16_t* W5h = (bf16_t*)(wb + 573440);    bf16_t* W5l = (bf16_t*)(wb + 638976);
  bf16_t* W6h = (bf16_t*)(wb + 704512);    bf16_t* W6l = (bf16_t*)(wb + 966656);
  bf16_t* W7h = (bf16_t*)(wb + 1228800);   bf16_t* W7l = (bf16_t*)(wb + 1294336);

  hipMemsetAsync(g, 0, 1024 * sizeof(float), stream);  // max identity (relu outputs >= 0)

  PrepAll pa;
  pa.seg[0] = {W2, W2h, W2l, 64, 64, 2};
  pa.seg[1] = {W3, W3h, W3l, 64, 64, 4};
  pa.seg[2] = {W4, W4h, W4l, 128, 128, 64};
  pa.seg[3] = {W5, W5h, W5l, 1088, 64, 16};   // W5[:, :64]
  pa.seg[4] = {W6, W6h, W6l, 512, 512, 64};
  pa.seg[5] = {W7, W7h, W7l, 256, 256, 16};
  kprep<<<166, 256, 0, stream>>>(pa);

  k1a<<<256, 256, 0, stream>>>(x, W1, b1, h1h, h1l);
  gemmS<2, 64, 0><<<dim3(256, 1), 256, 0, stream>>>(
      h1h, h1l, W2h, W2l, b2, 4, h2h, h2l, nullptr, nullptr, nullptr);        // L2
  m34<<<1024, 256, 0, stream>>>(h2h, h2l, W3h, W3l, b3, W4h, W4l, b4, gpart); // L3+L4+max
  kgmax<<<32, 256, 0, stream>>>(gpart, g);
  kc5<<<16, 256, 0, stream>>>(W5, b5, g, c5);
  mega2<<<1024, 256, 0, stream>>>(h2h, h2l, W5h, W5l, c5, W6h, W6l, b6,
                                  W7h, W7l, b7, W8, b8, out);                 // L5..L8
}

// Round 15
// 285.133 us; speedup vs baseline: 12.4670x; 12.4670x over previous
//
#include <hip/hip_runtime.h>

#define NPTS 65536

typedef __bf16 bf16_t;
typedef __bf16 bf16x8 __attribute__((ext_vector_type(8)));
typedef float f32x16 __attribute__((ext_vector_type(16)));

#define MFMA32(A, B, C) __builtin_amdgcn_mfma_f32_32x32x16_bf16(A, B, C, 0, 0, 0)

__device__ __forceinline__ float relu(float v) { return v > 0.f ? v : 0.f; }

// ======================================================================
// 128-pt-block layouts (R8-verified):
// Activation (C ch): octet idx = ((b*(C/16)+kc)*4+mi)*64 + l
//   point = b*128 + mi*32 + (l&31); channel = kc*16 + (l>>5)*8 + j
// Weight (N x K): octet idx = (st*(K/16)+kc)*64 + l; n = st*32+(l&31); k = kc*16+(l>>5)*8+j
// 64-pt internal contract (R10-verified): octet idx = (kc*2+mi)*64+l
// NOTE (R14 lesson): register double-buffers must be indexed by compile-time
// constants; rolled loops demote them to scratch (MfmaUtil 41% -> 1.2%).
// ======================================================================

struct PrepSeg { const float* src; bf16_t* h; bf16_t* l; int SW; int K; int nblk; };
struct PrepAll { PrepSeg seg[6]; };

__global__ __launch_bounds__(256) void kprep(PrepAll pa) {
  int blk = blockIdx.x, i = 0;
  while (blk >= pa.seg[i].nblk) { blk -= pa.seg[i].nblk; ++i; }
  const PrepSeg sg = pa.seg[i];
  int t8 = blk * 256 + threadIdx.x;
  int l = t8 & 63;
  int rest = t8 >> 6;
  int NKC = sg.K >> 4;
  int kc = rest % NKC, st = rest / NKC;
  int n = st * 32 + (l & 31);
  int k0 = kc * 16 + (l >> 5) * 8;
  const float* src = sg.src + (size_t)n * sg.SW + k0;
  bf16x8 hv, lv;
#pragma unroll
  for (int j = 0; j < 8; ++j) {
    float v = src[j];
    bf16_t h = (bf16_t)v;
    hv[j] = h; lv[j] = (bf16_t)(v - (float)h);
  }
  *(bf16x8*)(sg.h + (size_t)t8 * 8) = hv;
  *(bf16x8*)(sg.l + (size_t)t8 * 8) = lv;
}

// ============ k1a (verified): h1 = relu(x@W1.T+b1) in 128-pt activation order
__global__ __launch_bounds__(256, 2) void k1a(
    const float* __restrict__ x, const float* __restrict__ W1, const float* __restrict__ b1,
    bf16_t* __restrict__ h1h, bf16_t* __restrict__ h1l) {
  int p = blockIdx.x * 256 + threadIdx.x;
  float x0 = x[p * 3 + 0], x1 = x[p * 3 + 1], x2 = x[p * 3 + 2];
  int b = p >> 7, mi = (p >> 5) & 3, p31 = p & 31;
#pragma unroll
  for (int kc = 0; kc < 4; ++kc)
#pragma unroll
    for (int hbw = 0; hbw < 2; ++hbw) {
      bf16x8 hv, lv;
#pragma unroll
      for (int j = 0; j < 8; ++j) {
        int c = kc * 16 + hbw * 8 + j;
        float v = relu(fmaf(W1[c * 3], x0, fmaf(W1[c * 3 + 1], x1, fmaf(W1[c * 3 + 2], x2, b1[c]))));
        bf16_t h = (bf16_t)v;
        hv[j] = h; lv[j] = (bf16_t)(v - (float)h);
      }
      size_t off = (((size_t)(b * 4 + kc) * 4 + mi) * 64 + hbw * 32 + p31) * 8;
      *(bf16x8*)(h1h + off) = hv;
      *(bf16x8*)(h1l + off) = lv;
    }
}

// ============ gemmS (verified): D = W·X^T, 3-term split 32x32x16 bf16 MFMA
template <int PB, int K, int MODE>
__global__ __launch_bounds__(256, 3) void gemmS(
    const bf16_t* __restrict__ Ah, const bf16_t* __restrict__ Al,
    const bf16_t* __restrict__ Wh, const bf16_t* __restrict__ Wl,
    const float* __restrict__ bias, int nko,
    bf16_t* __restrict__ Oh, bf16_t* __restrict__ Ol,
    float* __restrict__ aux, const float* __restrict__ w8, const float* __restrict__ b8) {
  constexpr int WC = 4 / PB;
  constexpr int NKC = K / 16;
  constexpr int KG = 2;
  constexpr int NG = NKC / KG;
  __shared__ bf16_t smem[2][PB][2][KG * 2048];

  int tid = threadIdx.x;
  int lane = tid & 63;
  int w = __builtin_amdgcn_readfirstlane(tid >> 6);
  int rg = w / WC, cw = w % WC;
  int hb = lane >> 5, p31 = lane & 31;
  int bx = blockIdx.x;
  int st0 = blockIdx.y * WC + cw;
  int bblk = bx * PB + rg;

  f32x16 acc[4];
#pragma unroll
  for (int r = 0; r < 16; ++r) {
    float bv = bias[st0 * 32 + 8 * (r >> 2) + 4 * hb + (r & 3)];
#pragma unroll
    for (int mi = 0; mi < 4; ++mi) acc[mi][r] = bv;
  }

  auto stage = [&](int buf, int g) {
#pragma unroll
    for (int i = 0; i < PB * 4; ++i) {
      int u = i * 256 + tid;
      int rgs = u >> 10, rem = u & 1023;
      int t = rem >> 9, inner = rem & 511;
      const bf16_t* src = (t ? Al : Ah) +
          ((size_t)(bx * PB + rgs) * NKC + g * KG) * 2048 + inner * 8;
      *(bf16x8*)&smem[buf][rgs][t][inner * 8] = *(const bf16x8*)src;
    }
  };

  bf16x8 wch[KG], wcl[KG], wnh[KG], wnl[KG];
  auto wload = [&](int g, bf16x8* h, bf16x8* l) {
#pragma unroll
    for (int kcl = 0; kcl < KG; ++kcl) {
      size_t wo = (((size_t)st0 * NKC + g * KG + kcl) * 64 + lane) * 8;
      h[kcl] = *(const bf16x8*)(Wh + wo);
      l[kcl] = *(const bf16x8*)(Wl + wo);
    }
  };

  auto compute = [&](int buf, bf16x8* h, bf16x8* l) {
#pragma unroll
    for (int kcl = 0; kcl < KG; ++kcl)
#pragma unroll
      for (int mi = 0; mi < 4; ++mi) {
        const bf16_t* xp = &smem[buf][rg][0][((kcl * 4 + mi) * 64 + lane) * 8];
        bf16x8 xh = *(const bf16x8*)xp;
        bf16x8 xl = *(const bf16x8*)(xp + KG * 2048);
        acc[mi] = MFMA32(h[kcl], xh, acc[mi]);
        acc[mi] = MFMA32(l[kcl], xh, acc[mi]);
        acc[mi] = MFMA32(h[kcl], xl, acc[mi]);
      }
  };

  stage(0, 0);
  wload(0, wch, wcl);
  for (int g = 0; g < NG; ++g) {
    __syncthreads();
    if (g + 1 < NG) {
      stage((g + 1) & 1, g + 1);
      wload(g + 1, wnh, wnl);
    }
    compute(g & 1, wch, wcl);
#pragma unroll
    for (int kcl = 0; kcl < KG; ++kcl) { wch[kcl] = wnh[kcl]; wcl[kcl] = wnl[kcl]; }
  }

  if constexpr (MODE == 0) {
#pragma unroll
    for (int mi = 0; mi < 4; ++mi) {
      float a[16], rcv[8];
#pragma unroll
      for (int r = 0; r < 16; ++r) a[r] = relu(acc[mi][r]);
#pragma unroll
      for (int j = 0; j < 8; ++j) rcv[j] = __shfl_xor(hb ? a[j] : a[8 + j], 32);
      float o0[8], o1[8];
#pragma unroll
      for (int j = 0; j < 4; ++j) {
        o0[j]     = hb ? rcv[j]     : a[j];
        o0[4 + j] = hb ? a[8 + j]   : rcv[j];
        o1[j]     = hb ? rcv[4 + j] : a[4 + j];
        o1[4 + j] = hb ? a[12 + j]  : rcv[4 + j];
      }
      bf16x8 h0, l0, h1, l1;
#pragma unroll
      for (int j = 0; j < 8; ++j) {
        bf16_t x0 = (bf16_t)o0[j]; h0[j] = x0; l0[j] = (bf16_t)(o0[j] - (float)x0);
        bf16_t x1 = (bf16_t)o1[j]; h1[j] = x1; l1[j] = (bf16_t)(o1[j] - (float)x1);
      }
      int kco = st0 * 2 + hb;
      size_t ob = ((size_t)(bblk * nko + kco) * 4 + mi) * 64;
      *(bf16x8*)(Oh + (ob + p31) * 8)      = h0;
      *(bf16x8*)(Ol + (ob + p31) * 8)      = l0;
      *(bf16x8*)(Oh + (ob + 32 + p31) * 8) = h1;
      *(bf16x8*)(Ol + (ob + 32 + p31) * 8) = l1;
    }
  } else if constexpr (MODE == 1) {
#pragma unroll
    for (int r = 0; r < 16; ++r) {
      float m = relu(acc[0][r]);
#pragma unroll
      for (int mi = 1; mi < 4; ++mi) m = fmaxf(m, relu(acc[mi][r]));
#pragma unroll
      for (int off = 1; off < 32; off <<= 1) m = fmaxf(m, __shfl_xor(m, off));
      if (p31 == 0)
        aux[(size_t)bx * 1024 + st0 * 32 + 8 * (r >> 2) + 4 * hb + (r & 3)] = m;
    }
  } else {
    __shared__ float sp[4][128];
    float w8v[16];
#pragma unroll
    for (int r = 0; r < 16; ++r) w8v[r] = w8[st0 * 32 + 8 * (r >> 2) + 4 * hb + (r & 3)];
#pragma unroll
    for (int mi = 0; mi < 4; ++mi) {
      float s = 0.f;
#pragma unroll
      for (int r = 0; r < 16; ++r) s = fmaf(relu(acc[mi][r]), w8v[r], s);
      s += __shfl_xor(s, 32);
      if (hb == 0) sp[w][mi * 32 + p31] = s;
    }
    __syncthreads();
    if (tid < 128)
      aux[(size_t)bx * 128 + tid] = sp[0][tid] + sp[1][tid] + sp[2][tid] + sp[3][tid] + b8[0];
  }
}

// ============ kgmax (R10 verbatim): g[c] = max over gpart rows (poison rows are
// tiny-negative floats, harmless under fmaxf with m init 0)
__global__ __launch_bounds__(256) void kgmax(const float* __restrict__ gpart, float* __restrict__ g) {
  int t = blockIdx.x * 256 + threadIdx.x;  // 8192 threads
  int c = t & 1023, rg = t >> 10;
  const float* gp = gpart + (size_t)rg * 64 * 1024 + c;
  float m = 0.f;
#pragma unroll 8
  for (int r = 0; r < 64; ++r) m = fmaxf(m, gp[(size_t)r * 1024]);
  atomicMax((unsigned int*)(g + c), __float_as_uint(m));  // all values >= 0
}

// ============ kc5 (verified): c5[c] = W5[c][64:1088] @ g + b5[c]
__global__ __launch_bounds__(256) void kc5(
    const float* __restrict__ W5, const float* __restrict__ b5,
    const float* __restrict__ g, float* __restrict__ c5) {
  int tid = threadIdx.x;
  int ci = tid >> 3, kg = tid & 7;
  int c = blockIdx.x * 32 + ci;
  const float* wrow = W5 + (size_t)c * 1088 + 64 + kg * 128;
  const float* gp = g + kg * 128;
  float acc = 0.f;
#pragma unroll 8
  for (int k = 0; k < 128; ++k) acc += wrow[k] * gp[k];
#pragma unroll
  for (int off = 1; off <= 4; off <<= 1) acc += __shfl_xor(acc, off);
  if (kg == 0) c5[c] = acc + b5[c];
}

// ======================================================================
// Verified 64-pt helpers (R10)
// ======================================================================

struct Oct { bf16x8 h0, l0, h1, l1; };
__device__ __forceinline__ Oct epi_pack(const f32x16& accv, int hb) {
  float a[16], rcv[8];
#pragma unroll
  for (int r = 0; r < 16; ++r) a[r] = relu(accv[r]);
#pragma unroll
  for (int j = 0; j < 8; ++j) rcv[j] = __shfl_xor(hb ? a[j] : a[8 + j], 32);
  float o0[8], o1[8];
#pragma unroll
  for (int j = 0; j < 4; ++j) {
    o0[j]     = hb ? rcv[j]     : a[j];
    o0[4 + j] = hb ? a[8 + j]   : rcv[j];
    o1[j]     = hb ? rcv[4 + j] : a[4 + j];
    o1[4 + j] = hb ? a[12 + j]  : rcv[4 + j];
  }
  Oct o;
#pragma unroll
  for (int j = 0; j < 8; ++j) {
    bf16_t x0 = (bf16_t)o0[j]; o.h0[j] = x0; o.l0[j] = (bf16_t)(o0[j] - (float)x0);
    bf16_t x1 = (bf16_t)o1[j]; o.h1[j] = x1; o.l1[j] = (bf16_t)(o1[j] - (float)x1);
  }
  return o;
}

__device__ __forceinline__ void epi_store_lds(const Oct& o, bf16_t* H, bf16_t* L, int ob, int p31) {
  *(bf16x8*)(H + (ob + p31) * 8)      = o.h0;
  *(bf16x8*)(H + (ob + 32 + p31) * 8) = o.h1;
  *(bf16x8*)(L + (ob + p31) * 8)      = o.l0;
  *(bf16x8*)(L + (ob + 32 + p31) * 8) = o.l1;
}

__device__ __forceinline__ void binit2(f32x16 acc[2], const float* bias, int base, int hb) {
#pragma unroll
  for (int r = 0; r < 16; ++r) {
    float bv = bias[base + 8 * (r >> 2) + 4 * hb + (r & 3)];
    acc[0][r] = bv; acc[1][r] = bv;
  }
}

template <int NKC>
__device__ __forceinline__ void wgemm(const bf16_t* __restrict__ Wh, const bf16_t* __restrict__ Wl,
                                      int st, const bf16_t* act, int loOff, int lane,
                                      f32x16 acc[2]) {
#pragma unroll
  for (int kc = 0; kc < NKC; ++kc) {
    size_t wo = ((size_t)(st * NKC + kc) * 64 + lane) * 8;
    bf16x8 awh = *(const bf16x8*)(Wh + wo), awl = *(const bf16x8*)(Wl + wo);
    bf16x8 xh[2], xl[2];
#pragma unroll
    for (int mi = 0; mi < 2; ++mi) {
      const bf16_t* xp = act + ((kc * 2 + mi) * 64 + lane) * 8;
      xh[mi] = *(const bf16x8*)xp; xl[mi] = *(const bf16x8*)(xp + loOff);
    }
#pragma unroll
    for (int mi = 0; mi < 2; ++mi) acc[mi] = MFMA32(awh, xh[mi], acc[mi]);
#pragma unroll
    for (int mi = 0; mi < 2; ++mi) acc[mi] = MFMA32(awl, xh[mi], acc[mi]);
#pragma unroll
    for (int mi = 0; mi < 2; ++mi) acc[mi] = MFMA32(awh, xl[mi], acc[mi]);
  }
}

// ============ mega2: h2 -> z5 -> z6 -> z7 -> out, 64-pt blocks.
// R10 structure; z6->L7 done in two 128-ch halves so LDS = 48KB -> 3 blocks/CU.
__global__ __launch_bounds__(256, 3) void mega2(
    const bf16_t* __restrict__ h2gh, const bf16_t* __restrict__ h2gl,
    const bf16_t* __restrict__ W5h, const bf16_t* __restrict__ W5l, const float* __restrict__ c5,
    const bf16_t* __restrict__ W6h, const bf16_t* __restrict__ W6l, const float* __restrict__ b6,
    const bf16_t* __restrict__ W7h, const bf16_t* __restrict__ W7l, const float* __restrict__ b7,
    const float* __restrict__ w8, const float* __restrict__ b8v, float* __restrict__ out) {
  // phase A: h2 pair [0,8192), z5buf pair [8192,24576) elems.
  // phase B (per half): z6 half pair [0,16384) elems (hi [0,8192), lo +8192).
  __shared__ __align__(16) bf16_t smem[24576];
  __shared__ float sp[4][64];
  int tid = threadIdx.x, lane = tid & 63;
  int w = __builtin_amdgcn_readfirstlane(tid >> 6);
  int hb = lane >> 5, p31 = lane & 31;
  int b = blockIdx.x;
  int B = b >> 1, half = b & 1;
  bf16_t* z5buf = smem + 8192;

  // stage h2 (R10-verified remap from 128-pt producer layout)
#pragma unroll
  for (int i = 0; i < 4; ++i) {
    int u = i * 256 + tid;
    int t = u >> 9, rem = u & 511;
    int kcmi = rem >> 6, l = rem & 63;
    int kc = kcmi >> 1, mi2 = kcmi & 1;
    size_t so = ((size_t)((B * 4 + kc) * 4 + half * 2 + mi2) * 64 + l) * 8;
    const bf16_t* src = (t ? h2gl : h2gh) + so;
    *(bf16x8*)(smem + t * 4096 + rem * 8) = *(const bf16x8*)src;
  }
  __syncthreads();

  // z6 accumulators: wave owns strips {2w, 2w+1} (64 ch) x 64 pts
  f32x16 z6a[2][2];
#pragma unroll
  for (int s = 0; s < 2; ++s)
#pragma unroll
    for (int r = 0; r < 16; ++r) {
      float bv = b6[(w * 2 + s) * 32 + 8 * (r >> 2) + 4 * hb + (r & 3)];
      z6a[s][0][r] = bv; z6a[s][1][r] = bv;
    }

  for (int g5 = 0; g5 < 4; ++g5) {
    int st5 = g5 * 4 + w;
    f32x16 a5[2];
    binit2(a5, c5, st5 * 32, hb);
    wgemm<4>(W5h, W5l, st5, smem, 4096, lane, a5);
    __syncthreads();  // prev group's L6 reads of z5buf complete
#pragma unroll
    for (int mi = 0; mi < 2; ++mi) {
      Oct o = epi_pack(a5[mi], hb);
      epi_store_lds(o, z5buf, z5buf + 8192, ((w * 2 + hb) * 2 + mi) * 64, p31);
    }
    __syncthreads();  // z5buf ready
#pragma unroll
    for (int kc = 0; kc < 8; ++kc) {
      bf16x8 awh[2], awl[2], xh[2], xl[2];
#pragma unroll
      for (int s = 0; s < 2; ++s) {
        size_t wo = ((size_t)((w * 2 + s) * 32 + g5 * 8 + kc) * 64 + lane) * 8;
        awh[s] = *(const bf16x8*)(W6h + wo);
        awl[s] = *(const bf16x8*)(W6l + wo);
      }
#pragma unroll
      for (int mi = 0; mi < 2; ++mi) {
        const bf16_t* xp = z5buf + ((kc * 2 + mi) * 64 + lane) * 8;
        xh[mi] = *(const bf16x8*)xp; xl[mi] = *(const bf16x8*)(xp + 8192);
      }
#pragma unroll
      for (int s = 0; s < 2; ++s)
#pragma unroll
        for (int mi = 0; mi < 2; ++mi) z6a[s][mi] = MFMA32(awh[s], xh[mi], z6a[s][mi]);
#pragma unroll
      for (int s = 0; s < 2; ++s)
#pragma unroll
        for (int mi = 0; mi < 2; ++mi) z6a[s][mi] = MFMA32(awl[s], xh[mi], z6a[s][mi]);
#pragma unroll
      for (int s = 0; s < 2; ++s)
#pragma unroll
        for (int mi = 0; mi < 2; ++mi) z6a[s][mi] = MFMA32(awh[s], xl[mi], z6a[s][mi]);
    }
  }

  // ---- z6 -> L7 in two 128-ch halves (halves the LDS footprint vs R10)
  f32x16 a7[2];
  binit2(a7, b7, w * 32, hb);
#pragma unroll
  for (int h = 0; h < 2; ++h) {
    __syncthreads();  // h=0: phase-A reads done; h=1: L7 half-0 reads done
    if ((w >> 1) == h) {
#pragma unroll
      for (int s = 0; s < 2; ++s) {
        int kcl0 = ((w * 2 + s) - 4 * h) * 2 + hb;   // in [0,8)
#pragma unroll
        for (int mi = 0; mi < 2; ++mi) {
          Oct o = epi_pack(z6a[s][mi], hb);
          epi_store_lds(o, smem, smem + 8192, (kcl0 * 2 + mi) * 64, p31);
        }
      }
    }
    __syncthreads();  // z6 half ready
    // L7 partial over this half's 128 k: weight strip index 2w+h over NKC=8
    wgemm<8>(W7h, W7l, 2 * w + h, smem, 8192, lane, a7);
  }

  // ---- L8: dot with w8
  float w8v[16];
#pragma unroll
  for (int r = 0; r < 16; ++r) w8v[r] = w8[w * 32 + 8 * (r >> 2) + 4 * hb + (r & 3)];
#pragma unroll
  for (int mi = 0; mi < 2; ++mi) {
    float s = 0.f;
#pragma unroll
    for (int r = 0; r < 16; ++r) s = fmaf(relu(a7[mi][r]), w8v[r], s);
    s += __shfl_xor(s, 32);
    if (hb == 0) sp[w][mi * 32 + p31] = s;
  }
  __syncthreads();
  if (tid < 64)
    out[b * 64 + tid] = sp[0][tid] + sp[1][tid] + sp[2][tid] + sp[3][tid] + b8v[0];
}

extern "C" void kernel_launch(void* const* d_in, const int* in_sizes, int n_in,
                              void* d_out, int out_size, void* d_ws, size_t ws_size,
                              hipStream_t stream) {
  const float* x  = (const float*)d_in[0];
  const float* W1 = (const float*)d_in[1];  const float* b1 = (const float*)d_in[2];
  const float* W2 = (const float*)d_in[3];  const float* b2 = (const float*)d_in[4];
  const float* W3 = (const float*)d_in[5];  const float* b3 = (const float*)d_in[6];
  const float* W4 = (const float*)d_in[7];  const float* b4 = (const float*)d_in[8];
  const float* W5 = (const float*)d_in[9];  const float* b5 = (const float*)d_in[10];
  const float* W6 = (const float*)d_in[11]; const float* b6 = (const float*)d_in[12];
  const float* W7 = (const float*)d_in[13]; const float* b7 = (const float*)d_in[14];
  const float* W8 = (const float*)d_in[15]; const float* b8 = (const float*)d_in[16];
  float* out = (float*)d_out;

  // Workspace overlays (R10 verbatim):
  //   h2 pair [128,136)+[136,144)  L2->m... (L3/mega2)
  //   h1 pair [144,152)+[152,160)  k1a->L2
  //   y3 pair [144,160)+[160,176)  L3->L4  (over dead h1)
  //   gpart [208,210), g/c5 [210,..), weight frags after
  const size_t MB = 1ull << 20;
  char* ws = (char*)d_ws;
  bf16_t* h2h = (bf16_t*)(ws + 128 * MB);  bf16_t* h2l = (bf16_t*)(ws + 136 * MB);
  bf16_t* h1h = (bf16_t*)(ws + 144 * MB);  bf16_t* h1l = (bf16_t*)(ws + 152 * MB);
  bf16_t* y3h = (bf16_t*)(ws + 144 * MB);  bf16_t* y3l = (bf16_t*)(ws + 160 * MB);
  float* gpart = (float*)(ws + 208 * MB);
  float* g     = (float*)(ws + 210 * MB);
  float* c5    = (float*)(ws + 210 * MB + 4096);
  char* wb = ws + 210 * MB + 65536;
  bf16_t* W2h = (bf16_t*)(wb);             bf16_t* W2l = (bf16_t*)(wb + 8192);
  bf16_t* W3h = (bf16_t*)(wb + 16384);     bf16_t* W3l = (bf16_t*)(wb + 32768);
  bf16_t* W4h = (bf16_t*)(wb + 49152);     bf16_t* W4l = (bf16_t*)(wb + 311296);
  bf16_t* W5h = (bf16_t*)(wb + 573440);    bf16_t* W5l = (bf16_t*)(wb + 638976);
  bf16_t* W6h = (bf16_t*)(wb + 704512);    bf16_t* W6l = (bf16_t*)(wb + 966656);
  bf16_t* W7h = (bf16_t*)(wb + 1228800);   bf16_t* W7l = (bf16_t*)(wb + 1294336);

  hipMemsetAsync(g, 0, 1024 * sizeof(float), stream);  // max identity (relu outputs >= 0)

  PrepAll pa;
  pa.seg[0] = {W2, W2h, W2l, 64, 64, 2};
  pa.seg[1] = {W3, W3h, W3l, 64, 64, 4};
  pa.seg[2] = {W4, W4h, W4l, 128, 128, 64};
  pa.seg[3] = {W5, W5h, W5l, 1088, 64, 16};   // W5[:, :64]
  pa.seg[4] = {W6, W6h, W6l, 512, 512, 64};
  pa.seg[5] = {W7, W7h, W7l, 256, 256, 16};
  kprep<<<166, 256, 0, stream>>>(pa);

  k1a<<<256, 256, 0, stream>>>(x, W1, b1, h1h, h1l);
  gemmS<2, 64, 0><<<dim3(256, 1), 256, 0, stream>>>(
      h1h, h1l, W2h, W2l, b2, 4, h2h, h2l, nullptr, nullptr, nullptr);        // L2
  gemmS<1, 64, 0><<<dim3(512, 1), 256, 0, stream>>>(
      h2h, h2l, W3h, W3l, b3, 8, y3h, y3l, nullptr, nullptr, nullptr);        // L3
  gemmS<1, 128, 1><<<dim3(512, 8), 256, 0, stream>>>(
      y3h, y3l, W4h, W4l, b4, 0, nullptr, nullptr, gpart, nullptr, nullptr);  // L4 + max
  kgmax<<<32, 256, 0, stream>>>(gpart, g);
  kc5<<<16, 256, 0, stream>>>(W5, b5, g, c5);
  mega2<<<1024, 256, 0, stream>>>(h2h, h2l, W5h, W5l, c5, W6h, W6l, b6,
                                  W7h, W7l, b7, W8, b8, out);                 // L5..L8
}